// Round 5
// baseline (1732.997 us; speedup 1.0000x reference)
//
#include <hip/hip_runtime.h>

#define N_NODES 100000
#define N_EDGES 3200000
#define BATCH 16
#define BKT_SHIFT 6
#define BKT_NODES 64                                   // nodes per bucket
#define K_BUCKETS ((N_NODES + BKT_NODES - 1) / BKT_NODES)  // 1563
#define CNT_STRIDE 16                                  // one counter per 64B line
#define SCAN_T 256
#define SCAN_C 7                                       // 256*7 = 1792 >= 1563

// ---------------- phase 1: bucket histogram ----------------
__global__ void hist_kernel(const int* __restrict__ row, int* __restrict__ cnt) {
    int e = blockIdx.x * blockDim.x + threadIdx.x;
    if (e < N_EDGES) atomicAdd(&cnt[(row[e] >> BKT_SHIFT) * CNT_STRIDE], 1);
}

// ---------------- phase 2: exclusive scan of 1563 bucket counts ----------
__global__ void scan_kernel(const int* __restrict__ cnt, int* __restrict__ bptr) {
    __shared__ int s[SCAN_T];
    int t = threadIdx.x;
    int loc[SCAN_C];
    int sum = 0;
    for (int i = 0; i < SCAN_C; i++) {
        int idx = t * SCAN_C + i;
        int v = (idx < K_BUCKETS) ? cnt[idx * CNT_STRIDE] : 0;
        loc[i] = v;
        sum += v;
    }
    s[t] = sum;
    __syncthreads();
    for (int off = 1; off < SCAN_T; off <<= 1) {   // Hillis-Steele inclusive
        int x = (t >= off) ? s[t - off] : 0;
        __syncthreads();
        s[t] += x;
        __syncthreads();
    }
    int excl = s[t] - sum;                          // exclusive prefix of chunk
    for (int i = 0; i < SCAN_C; i++) {
        int idx = t * SCAN_C + i;
        if (idx < K_BUCKETS) bptr[idx] = excl;
        excl += loc[i];
    }
    if (t == 0) bptr[K_BUCKETS] = N_EDGES;
}

// ---------------- phase 3: bin edges (bucket-contiguous append) ----------
// record: x = (r_local << 17) | col   (col < 2^17, r_local < 64), y = w bits
__global__ void fill_kernel(const int* __restrict__ row, const int* __restrict__ col,
                            const float* __restrict__ w,
                            const int* __restrict__ bptr, int* __restrict__ cursor,
                            uint2* __restrict__ entries) {
    int e = blockIdx.x * blockDim.x + threadIdx.x;
    if (e >= N_EDGES) return;
    int r = row[e];
    int bkt = r >> BKT_SHIFT;
    int pos = bptr[bkt] + atomicAdd(&cursor[bkt * CNT_STRIDE], 1);
    entries[pos] = make_uint2(((unsigned)(r & (BKT_NODES - 1)) << 17) | (unsigned)col[e],
                              __float_as_uint(w[e]));
}

// ---------------- phase 4: one layer, LDS-privatized push ----------------
// One block per bucket. 16 lanes per edge record; the y[col] gather consumes
// exactly one full 64B line per edge. Accumulate with ds_add_f32 into a 4KB
// LDS tile, then one coalesced store per bucket. Zero global atomics.
__global__ void layer_kernel(const float* __restrict__ y,
                             const uint2* __restrict__ entries,
                             const int* __restrict__ bptr,
                             float* __restrict__ out) {
    __shared__ float acc[BKT_NODES * BATCH];        // 4KB
    int t = threadIdx.x;
    for (int i = t; i < BKT_NODES * BATCH; i += 256) acc[i] = 0.f;
    __syncthreads();

    int b = blockIdx.x;
    int beg = bptr[b];
    int end = bptr[b + 1];
    int lane_b = t & 15;
    int g = t >> 4;                                 // 16 groups of 16 lanes
    for (int i = beg + g; i < end; i += 16) {
        uint2 rec = entries[i];
        int c = (int)(rec.x & 0x1FFFFu);
        int rl = (int)(rec.x >> 17);
        float v = __uint_as_float(rec.y) * y[c * BATCH + lane_b];
        atomicAdd(&acc[rl * BATCH + lane_b], v);
    }
    __syncthreads();

    int base = b * BKT_NODES * BATCH;
    for (int i = t; i < BKT_NODES * BATCH; i += 256) {
        int gi = base + i;
        if (gi < N_NODES * BATCH) out[gi] = acc[i];
    }
}

extern "C" void kernel_launch(void* const* d_in, const int* in_sizes, int n_in,
                              void* d_out, int out_size, void* d_ws, size_t ws_size,
                              hipStream_t stream) {
    const float* x   = (const float*)d_in[0];
    const float* w   = (const float*)d_in[1];
    const int*   row = (const int*)d_in[2];
    const int*   col = (const int*)d_in[3];
    float*       out = (float*)d_out;

    // ---- workspace carve-up (~32.3 MB; round 3 proved ws >= 33.3 MB) ----
    char* p = (char*)d_ws;
    uint2* entries = (uint2*)p;  p += (size_t)N_EDGES * sizeof(uint2);           // 25.6 MB
    float* buf     = (float*)p;  p += (size_t)N_NODES * BATCH * sizeof(float);   // 6.4 MB
    int* cnt       = (int*)p;    p += (size_t)K_BUCKETS * CNT_STRIDE * sizeof(int); // 100 KB
    int* cursor    = (int*)p;    p += (size_t)K_BUCKETS * CNT_STRIDE * sizeof(int); // 100 KB
    int* bptr      = (int*)p;    p += (size_t)(K_BUCKETS + 1) * sizeof(int);

    hipMemsetAsync(cnt, 0, (size_t)K_BUCKETS * CNT_STRIDE * sizeof(int), stream);
    hipMemsetAsync(cursor, 0, (size_t)K_BUCKETS * CNT_STRIDE * sizeof(int), stream);

    // ---- build binned edge list (once; reused by all 4 layers) ----
    const int eblocks = (N_EDGES + 255) / 256;      // 12500
    hist_kernel<<<eblocks, 256, 0, stream>>>(row, cnt);
    scan_kernel<<<1, SCAN_T, 0, stream>>>(cnt, bptr);
    fill_kernel<<<eblocks, 256, 0, stream>>>(row, col, w, bptr, cursor, entries);

    // ---- 4 layers; d_out doubles as ping-pong buffer ----
    layer_kernel<<<K_BUCKETS, 256, 0, stream>>>(x,   entries, bptr, buf);  // x   -> buf
    layer_kernel<<<K_BUCKETS, 256, 0, stream>>>(buf, entries, bptr, out);  // buf -> out
    layer_kernel<<<K_BUCKETS, 256, 0, stream>>>(out, entries, bptr, buf);  // out -> buf
    layer_kernel<<<K_BUCKETS, 256, 0, stream>>>(buf, entries, bptr, out);  // buf -> out
}

// Round 6
// 1535.929 us; speedup vs baseline: 1.1283x; 1.1283x over previous
//
#include <hip/hip_runtime.h>

#define N_NODES 100000
#define N_EDGES 3200000
#define BATCH 16
#define BKT_SHIFT 6
#define BKT_NODES 64                                   // nodes per bucket
#define K_BUCKETS ((N_NODES + BKT_NODES - 1) / BKT_NODES)  // 1563
#define CNT_STRIDE 16                                  // one counter per 64B line
#define SCAN_T 256
#define SCAN_C 7                                       // 256*7 = 1792 >= 1563
#define SPLIT 2                                        // blocks per bucket

// ---------------- phase 1: bucket histogram ----------------
__global__ void hist_kernel(const int* __restrict__ row, int* __restrict__ cnt) {
    int e = blockIdx.x * blockDim.x + threadIdx.x;
    if (e < N_EDGES) atomicAdd(&cnt[(row[e] >> BKT_SHIFT) * CNT_STRIDE], 1);
}

// ---------------- phase 2: exclusive scan of 1563 bucket counts ----------
__global__ void scan_kernel(const int* __restrict__ cnt, int* __restrict__ bptr) {
    __shared__ int s[SCAN_T];
    int t = threadIdx.x;
    int loc[SCAN_C];
    int sum = 0;
    for (int i = 0; i < SCAN_C; i++) {
        int idx = t * SCAN_C + i;
        int v = (idx < K_BUCKETS) ? cnt[idx * CNT_STRIDE] : 0;
        loc[i] = v;
        sum += v;
    }
    s[t] = sum;
    __syncthreads();
    for (int off = 1; off < SCAN_T; off <<= 1) {   // Hillis-Steele inclusive
        int x = (t >= off) ? s[t - off] : 0;
        __syncthreads();
        s[t] += x;
        __syncthreads();
    }
    int excl = s[t] - sum;                          // exclusive prefix of chunk
    for (int i = 0; i < SCAN_C; i++) {
        int idx = t * SCAN_C + i;
        if (idx < K_BUCKETS) bptr[idx] = excl;
        excl += loc[i];
    }
    if (t == 0) bptr[K_BUCKETS] = N_EDGES;
}

// ---------------- phase 3: bin edges (bucket-contiguous append) ----------
// record: x = (r_local << 17) | col   (col < 2^17, r_local < 64), y = w bits
__global__ void fill_kernel(const int* __restrict__ row, const int* __restrict__ col,
                            const float* __restrict__ w,
                            const int* __restrict__ bptr, int* __restrict__ cursor,
                            uint2* __restrict__ entries) {
    int e = blockIdx.x * blockDim.x + threadIdx.x;
    if (e >= N_EDGES) return;
    int r = row[e];
    int bkt = r >> BKT_SHIFT;
    int pos = bptr[bkt] + atomicAdd(&cursor[bkt * CNT_STRIDE], 1);
    entries[pos] = make_uint2(((unsigned)(r & (BKT_NODES - 1)) << 17) | (unsigned)col[e],
                              __float_as_uint(w[e]));
}

// ---------------- phase 4: one layer, LDS-privatized push ----------------
// SPLIT blocks per bucket; each block streams its record segment with
// 8-record batches (8 independent gathers in flight per wave chain), LDS
// ds_add_f32 accumulate, then a coalesced global atomicAdd tile combine.
// out must be zeroed before launch.
__global__ void layer_kernel(const float* __restrict__ y,
                             const uint2* __restrict__ entries,
                             const int* __restrict__ bptr,
                             float* __restrict__ out) {
    __shared__ float acc[BKT_NODES * BATCH];        // 4KB
    int t = threadIdx.x;
    for (int i = t; i < BKT_NODES * BATCH; i += 256) acc[i] = 0.f;
    __syncthreads();

    int b  = blockIdx.x >> 1;                       // bucket
    int sg = blockIdx.x & 1;                        // segment within bucket
    int beg = bptr[b], end = bptr[b + 1];
    int mid = beg + ((end - beg) >> 1);
    int s0 = sg ? mid : beg;
    int s1 = sg ? end : mid;

    int lane_b = t & 15;
    int g = t >> 4;                                 // 16 groups of 16 lanes
    for (int i0 = s0 + g * 8; i0 < s1; i0 += 16 * 8) {
        if (i0 + 8 <= s1) {
            uint2 rec[8];
            #pragma unroll
            for (int j = 0; j < 8; j++) rec[j] = entries[i0 + j];
            float yv[8];
            #pragma unroll
            for (int j = 0; j < 8; j++)
                yv[j] = y[(int)(rec[j].x & 0x1FFFFu) * BATCH + lane_b];
            #pragma unroll
            for (int j = 0; j < 8; j++)
                atomicAdd(&acc[(int)(rec[j].x >> 17) * BATCH + lane_b],
                          __uint_as_float(rec[j].y) * yv[j]);
        } else {
            for (int i = i0; i < s1; i++) {
                uint2 rec = entries[i];
                float v = __uint_as_float(rec.y) *
                          y[(int)(rec.x & 0x1FFFFu) * BATCH + lane_b];
                atomicAdd(&acc[(int)(rec.x >> 17) * BATCH + lane_b], v);
            }
        }
    }
    __syncthreads();

    int base = b * BKT_NODES * BATCH;
    for (int i = t; i < BKT_NODES * BATCH; i += 256) {
        int gi = base + i;
        if (gi < N_NODES * BATCH) atomicAdd(&out[gi], acc[i]);
    }
}

extern "C" void kernel_launch(void* const* d_in, const int* in_sizes, int n_in,
                              void* d_out, int out_size, void* d_ws, size_t ws_size,
                              hipStream_t stream) {
    const float* x   = (const float*)d_in[0];
    const float* w   = (const float*)d_in[1];
    const int*   row = (const int*)d_in[2];
    const int*   col = (const int*)d_in[3];
    float*       out = (float*)d_out;

    const size_t state_bytes = (size_t)N_NODES * BATCH * sizeof(float);  // 6.4 MB

    // ---- workspace carve-up (~32.3 MB; round 3 proved ws >= 33.3 MB) ----
    char* p = (char*)d_ws;
    uint2* entries = (uint2*)p;  p += (size_t)N_EDGES * sizeof(uint2);           // 25.6 MB
    float* buf     = (float*)p;  p += state_bytes;                               // 6.4 MB
    int* cnt       = (int*)p;    p += (size_t)K_BUCKETS * CNT_STRIDE * sizeof(int);
    int* cursor    = (int*)p;    p += (size_t)K_BUCKETS * CNT_STRIDE * sizeof(int);
    int* bptr      = (int*)p;    p += (size_t)(K_BUCKETS + 1) * sizeof(int);

    hipMemsetAsync(cnt, 0, (size_t)K_BUCKETS * CNT_STRIDE * sizeof(int), stream);
    hipMemsetAsync(cursor, 0, (size_t)K_BUCKETS * CNT_STRIDE * sizeof(int), stream);

    // ---- build binned edge list (once; reused by all 4 layers) ----
    const int eblocks = (N_EDGES + 255) / 256;      // 12500
    hist_kernel<<<eblocks, 256, 0, stream>>>(row, cnt);
    scan_kernel<<<1, SCAN_T, 0, stream>>>(cnt, bptr);
    fill_kernel<<<eblocks, 256, 0, stream>>>(row, col, w, bptr, cursor, entries);

    // ---- 4 layers; d_out doubles as ping-pong buffer ----
    const int lgrid = K_BUCKETS * SPLIT;            // 3126 blocks
    hipMemsetAsync(buf, 0, state_bytes, stream);
    layer_kernel<<<lgrid, 256, 0, stream>>>(x,   entries, bptr, buf);  // x   -> buf
    hipMemsetAsync(d_out, 0, state_bytes, stream);
    layer_kernel<<<lgrid, 256, 0, stream>>>(buf, entries, bptr, out);  // buf -> out
    hipMemsetAsync(buf, 0, state_bytes, stream);
    layer_kernel<<<lgrid, 256, 0, stream>>>(out, entries, bptr, buf);  // out -> buf
    hipMemsetAsync(d_out, 0, state_bytes, stream);
    layer_kernel<<<lgrid, 256, 0, stream>>>(buf, entries, bptr, out);  // buf -> out
}

// Round 7
// 408.514 us; speedup vs baseline: 4.2422x; 3.7598x over previous
//
#include <hip/hip_runtime.h>

#define N_NODES 100000
#define N_EDGES 3200000
#define BATCH 16
#define BKT_SHIFT 6
#define BKT_NODES 64
#define K_BUCKETS 1563                 // ceil(100000/64)
#define NB 256                         // hist/fill blocks (E/NB = 12500 exact)
#define CHUNK (N_EDGES / NB)
#define SCAN_T 256
#define SCAN_C 7                       // 256*7 = 1792 >= 1563
#define CAP 4096                       // nodesort LDS capacity (bucket avg 2047, sigma 45)

// ---- phase 1: per-block LDS histogram of row-buckets (no global atomics) ----
__global__ void hist_kernel(const int* __restrict__ row, int* __restrict__ blk_cnt) {
    __shared__ int lh[K_BUCKETS];
    int t = threadIdx.x, blk = blockIdx.x;
    for (int k = t; k < K_BUCKETS; k += 256) lh[k] = 0;
    __syncthreads();
    int base = blk * CHUNK;
    for (int e = base + t; e < base + CHUNK; e += 256)
        atomicAdd(&lh[row[e] >> BKT_SHIFT], 1);
    __syncthreads();
    for (int k = t; k < K_BUCKETS; k += 256)
        blk_cnt[k * NB + blk] = lh[k];
}

// ---- phase 2: per-bucket exclusive prefix over the NB blocks; bucket totals ----
__global__ void colscan_kernel(int* __restrict__ blk_cnt, int* __restrict__ totals) {
    int bkt = blockIdx.x * blockDim.x + threadIdx.x;
    if (bkt >= K_BUCKETS) return;
    int4* p = (int4*)&blk_cnt[bkt * NB];
    int acc = 0;
    for (int q = 0; q < NB / 4; q++) {
        int4 v = p[q];
        int4 o;
        o.x = acc; acc += v.x;
        o.y = acc; acc += v.y;
        o.z = acc; acc += v.z;
        o.w = acc; acc += v.w;
        p[q] = o;
    }
    totals[bkt] = acc;
}

// ---- phase 3: exclusive scan of 1563 bucket totals -> bptr ----
__global__ void scan_kernel(const int* __restrict__ totals, int* __restrict__ bptr,
                            int* __restrict__ row_ptr) {
    __shared__ int s[SCAN_T];
    int t = threadIdx.x;
    int loc[SCAN_C];
    int sum = 0;
    for (int i = 0; i < SCAN_C; i++) {
        int idx = t * SCAN_C + i;
        int v = (idx < K_BUCKETS) ? totals[idx] : 0;
        loc[i] = v;
        sum += v;
    }
    s[t] = sum;
    __syncthreads();
    for (int off = 1; off < SCAN_T; off <<= 1) {   // Hillis-Steele inclusive
        int x = (t >= off) ? s[t - off] : 0;
        __syncthreads();
        s[t] += x;
        __syncthreads();
    }
    int excl = s[t] - sum;
    for (int i = 0; i < SCAN_C; i++) {
        int idx = t * SCAN_C + i;
        if (idx < K_BUCKETS) bptr[idx] = excl;
        excl += loc[i];
    }
    if (t == 0) { bptr[K_BUCKETS] = N_EDGES; row_ptr[N_NODES] = N_EDGES; }
}

// ---- phase 4: bin records; LDS-only cursors, zero global atomics ----
// record: x = (r_local<<17)|col (col<2^17), y = w bits. Each block's records
// per bucket land in a contiguous run (avg 12500/1563 ~ 8 recs = one 64B line).
__global__ void fill_kernel(const int* __restrict__ row, const int* __restrict__ col,
                            const float* __restrict__ w,
                            const int* __restrict__ bptr, const int* __restrict__ blk_cnt,
                            uint2* __restrict__ entries) {
    __shared__ int lbase[K_BUCKETS];
    __shared__ int lcur[K_BUCKETS];
    int t = threadIdx.x, blk = blockIdx.x;
    for (int k = t; k < K_BUCKETS; k += 256) {
        lbase[k] = bptr[k] + blk_cnt[k * NB + blk];
        lcur[k] = 0;
    }
    __syncthreads();
    int base = blk * CHUNK;
    for (int e = base + t; e < base + CHUNK; e += 256) {
        int r = row[e];
        int bkt = r >> BKT_SHIFT;
        int loc = atomicAdd(&lcur[bkt], 1);
        entries[lbase[bkt] + loc] =
            make_uint2(((unsigned)(r & (BKT_NODES - 1)) << 17) | (unsigned)col[e],
                       __float_as_uint(w[e]));
    }
}

// ---- phase 5: in-place per-bucket sort by node (LDS-staged); emits row_ptr ----
__global__ void nodesort_kernel(const int* __restrict__ bptr, uint2* __restrict__ entries,
                                int* __restrict__ row_ptr) {
    __shared__ uint2 ebuf[CAP];          // 32 KB
    __shared__ int nh[BKT_NODES];
    __shared__ int nc[BKT_NODES];
    int t = threadIdx.x, b = blockIdx.x;
    int beg = bptr[b], end = bptr[b + 1];
    int n = min(end - beg, CAP);
    if (t < BKT_NODES) nh[t] = 0;
    __syncthreads();
    for (int k = t; k < n; k += 256) {
        uint2 r = entries[beg + k];
        ebuf[k] = r;
        atomicAdd(&nh[r.x >> 17], 1);
    }
    __syncthreads();
    if (t == 0) {
        int acc = 0;
        for (int i = 0; i < BKT_NODES; i++) {
            int v = nh[i];
            int node = b * BKT_NODES + i;
            if (node < N_NODES) row_ptr[node] = beg + acc;
            nc[i] = acc;
            acc += v;
        }
    }
    __syncthreads();
    for (int k = t; k < n; k += 256) {
        uint2 r = ebuf[k];
        int pos = atomicAdd(&nc[r.x >> 17], 1);
        entries[beg + pos] = r;
    }
}

// ---- layer: node-parallel CSR pull, manual 8-deep software pipeline ----
// 16 lanes per node (one per batch column). Prefetch registers are carried
// across loop iterations (loop-carried dep -> compiler cannot collapse into
// serial load-use pairs). 8 independent gathers + 8 prefetches in flight.
__global__ void __launch_bounds__(256) pull_kernel(const float* __restrict__ y,
                            const uint2* __restrict__ entries,
                            const int* __restrict__ row_ptr,
                            float* __restrict__ out) {
    int tid = blockIdx.x * blockDim.x + threadIdx.x;
    int node = tid >> 4;
    int b = tid & 15;
    if (node >= N_NODES) return;
    int i = row_ptr[node];
    int end = row_ptr[node + 1];
    float acc = 0.f;
    if (i < end) {
        int lim = end - 1;
        uint2 r[8];
        #pragma unroll
        for (int j = 0; j < 8; j++) r[j] = entries[min(i + j, lim)];
        while (i + 8 <= end) {
            float yv[8];
            #pragma unroll
            for (int j = 0; j < 8; j++)
                yv[j] = y[(r[j].x & 0x1FFFFu) * BATCH + b];
            uint2 nx[8];
            #pragma unroll
            for (int j = 0; j < 8; j++)
                nx[j] = entries[min(i + 8 + j, lim)];
            #pragma unroll
            for (int j = 0; j < 8; j++)
                acc += __uint_as_float(r[j].y) * yv[j];
            #pragma unroll
            for (int j = 0; j < 8; j++) r[j] = nx[j];
            i += 8;
        }
        for (; i < end; i++) {              // tail: re-read (cheap, <8 records)
            uint2 rr = entries[i];
            acc += __uint_as_float(rr.y) * y[(rr.x & 0x1FFFFu) * BATCH + b];
        }
    }
    out[node * BATCH + b] = acc;
}

extern "C" void kernel_launch(void* const* d_in, const int* in_sizes, int n_in,
                              void* d_out, int out_size, void* d_ws, size_t ws_size,
                              hipStream_t stream) {
    const float* x   = (const float*)d_in[0];
    const float* w   = (const float*)d_in[1];
    const int*   row = (const int*)d_in[2];
    const int*   col = (const int*)d_in[3];
    float*       out = (float*)d_out;

    // ---- workspace carve-up (~32.4 MB; proven ws >= 33.25 MB) ----
    char* p = (char*)d_ws;
    uint2* entries = (uint2*)p;  p += (size_t)N_EDGES * sizeof(uint2);           // 25.6 MB
    float* buf     = (float*)p;                                                   // 6.4 MB
    int*   blk_cnt = (int*)buf;  // 1.6 MB alias: dead before first pull writes buf
    p += (size_t)N_NODES * BATCH * sizeof(float);
    int* totals  = (int*)p;      p += 8192;
    int* bptr    = (int*)p;      p += 8192;
    int* row_ptr = (int*)p;      // 400 KB

    // ---- build exact per-node CSR (once; reused by all 4 layers) ----
    hist_kernel<<<NB, 256, 0, stream>>>(row, blk_cnt);
    colscan_kernel<<<(K_BUCKETS + 255) / 256, 256, 0, stream>>>(blk_cnt, totals);
    scan_kernel<<<1, SCAN_T, 0, stream>>>(totals, bptr, row_ptr);
    fill_kernel<<<NB, 256, 0, stream>>>(row, col, w, bptr, blk_cnt, entries);
    nodesort_kernel<<<K_BUCKETS, 256, 0, stream>>>(bptr, entries, row_ptr);

    // ---- 4 pull layers; d_out doubles as ping-pong buffer, no memsets ----
    const int pgrid = (N_NODES * BATCH + 255) / 256;   // 6250 blocks
    pull_kernel<<<pgrid, 256, 0, stream>>>(x,   entries, row_ptr, buf);  // x   -> buf
    pull_kernel<<<pgrid, 256, 0, stream>>>(buf, entries, row_ptr, out);  // buf -> out
    pull_kernel<<<pgrid, 256, 0, stream>>>(out, entries, row_ptr, buf);  // out -> buf
    pull_kernel<<<pgrid, 256, 0, stream>>>(buf, entries, row_ptr, out);  // buf -> out
}

// Round 8
// 363.835 us; speedup vs baseline: 4.7631x; 1.1228x over previous
//
#include <hip/hip_runtime.h>

#define N_NODES 100000
#define N_EDGES 3200000
#define BATCH 16
#define BKT_SHIFT 6
#define BKT_NODES 64
#define K_BUCKETS 1563                 // ceil(100000/64)
#define NB 128                         // hist/fill blocks (E/NB = 25000 exact)
#define FT 512                         // hist/fill threads per block
#define CHUNK (N_EDGES / NB)
#define SCAN_T 256
#define SCAN_C 7                       // 256*7 = 1792 >= 1563
#define CAP 4096                       // nodesort LDS capacity (bucket avg 2047, sigma 45)

// ---- phase 1: per-block LDS histogram of row-buckets (no global atomics) ----
__global__ void hist_kernel(const int* __restrict__ row, int* __restrict__ blk_cnt) {
    __shared__ int lh[K_BUCKETS];
    int t = threadIdx.x, blk = blockIdx.x;
    for (int k = t; k < K_BUCKETS; k += FT) lh[k] = 0;
    __syncthreads();
    int base = blk * CHUNK;
    for (int e = base + t; e < base + CHUNK; e += FT)
        atomicAdd(&lh[row[e] >> BKT_SHIFT], 1);
    __syncthreads();
    for (int k = t; k < K_BUCKETS; k += FT)
        blk_cnt[k * NB + blk] = lh[k];
}

// ---- phase 2: per-bucket exclusive prefix over the NB blocks; bucket totals ----
__global__ void colscan_kernel(int* __restrict__ blk_cnt, int* __restrict__ totals) {
    int bkt = blockIdx.x * blockDim.x + threadIdx.x;
    if (bkt >= K_BUCKETS) return;
    int4* p = (int4*)&blk_cnt[bkt * NB];
    int acc = 0;
    for (int q = 0; q < NB / 4; q++) {
        int4 v = p[q];
        int4 o;
        o.x = acc; acc += v.x;
        o.y = acc; acc += v.y;
        o.z = acc; acc += v.z;
        o.w = acc; acc += v.w;
        p[q] = o;
    }
    totals[bkt] = acc;
}

// ---- phase 3: exclusive scan of 1563 bucket totals -> bptr ----
__global__ void scan_kernel(const int* __restrict__ totals, int* __restrict__ bptr,
                            int* __restrict__ row_ptr) {
    __shared__ int s[SCAN_T];
    int t = threadIdx.x;
    int loc[SCAN_C];
    int sum = 0;
    for (int i = 0; i < SCAN_C; i++) {
        int idx = t * SCAN_C + i;
        int v = (idx < K_BUCKETS) ? totals[idx] : 0;
        loc[i] = v;
        sum += v;
    }
    s[t] = sum;
    __syncthreads();
    for (int off = 1; off < SCAN_T; off <<= 1) {   // Hillis-Steele inclusive
        int x = (t >= off) ? s[t - off] : 0;
        __syncthreads();
        s[t] += x;
        __syncthreads();
    }
    int excl = s[t] - sum;
    for (int i = 0; i < SCAN_C; i++) {
        int idx = t * SCAN_C + i;
        if (idx < K_BUCKETS) bptr[idx] = excl;
        excl += loc[i];
    }
    if (t == 0) { bptr[K_BUCKETS] = N_EDGES; row_ptr[N_NODES] = N_EDGES; }
}

// ---- phase 4: bin records; LDS-only cursors, zero global atomics ----
// record: x = (r_local<<17)|col (col<2^17), y = w bits. Each block's records
// per bucket form a contiguous run (avg 25000/1563 ~ 16 recs = 128B), so
// boundary false-sharing is ~1 shared line per 2 full lines (vs 3.1x amp at
// 8-rec runs in round 7).
__global__ void fill_kernel(const int* __restrict__ row, const int* __restrict__ col,
                            const float* __restrict__ w,
                            const int* __restrict__ bptr, const int* __restrict__ blk_cnt,
                            uint2* __restrict__ entries) {
    __shared__ int lbase[K_BUCKETS];
    __shared__ int lcur[K_BUCKETS];
    int t = threadIdx.x, blk = blockIdx.x;
    for (int k = t; k < K_BUCKETS; k += FT) {
        lbase[k] = bptr[k] + blk_cnt[k * NB + blk];
        lcur[k] = 0;
    }
    __syncthreads();
    int base = blk * CHUNK;
    for (int e = base + t; e < base + CHUNK; e += FT) {
        int r = row[e];
        int bkt = r >> BKT_SHIFT;
        int loc = atomicAdd(&lcur[bkt], 1);
        entries[lbase[bkt] + loc] =
            make_uint2(((unsigned)(r & (BKT_NODES - 1)) << 17) | (unsigned)col[e],
                       __float_as_uint(w[e]));
    }
}

// ---- phase 5: in-place per-bucket sort by node (LDS-staged); emits row_ptr ----
__global__ void nodesort_kernel(const int* __restrict__ bptr, uint2* __restrict__ entries,
                                int* __restrict__ row_ptr) {
    __shared__ uint2 ebuf[CAP];          // 32 KB
    __shared__ int nh[BKT_NODES];
    __shared__ int nc[BKT_NODES];
    int t = threadIdx.x, b = blockIdx.x;
    int beg = bptr[b], end = bptr[b + 1];
    int n = min(end - beg, CAP);
    if (t < BKT_NODES) nh[t] = 0;
    __syncthreads();
    for (int k = t; k < n; k += 256) {
        uint2 r = entries[beg + k];
        ebuf[k] = r;
        atomicAdd(&nh[r.x >> 17], 1);
    }
    __syncthreads();
    if (t == 0) {
        int acc = 0;
        for (int i = 0; i < BKT_NODES; i++) {
            int v = nh[i];
            int node = b * BKT_NODES + i;
            if (node < N_NODES) row_ptr[node] = beg + acc;
            nc[i] = acc;
            acc += v;
        }
    }
    __syncthreads();
    for (int k = t; k < n; k += 256) {
        uint2 r = ebuf[k];
        int pos = atomicAdd(&nc[r.x >> 17], 1);
        entries[beg + pos] = r;
    }
}

// ---- layer: node-parallel CSR pull, 8-deep software pipeline, NO serial tail
// 16 lanes per node (one per batch column). Prefetch registers are carried
// across loop iterations. After the main loop, r[] already holds the
// clamp-loaded remainder; the epilogue gathers all 8 (duplicates hit L1) and
// predicates the FMA -> every edge is serviced by pipelined batched loads.
__global__ void __launch_bounds__(256) pull_kernel(const float* __restrict__ y,
                            const uint2* __restrict__ entries,
                            const int* __restrict__ row_ptr,
                            float* __restrict__ out) {
    int tid = blockIdx.x * blockDim.x + threadIdx.x;
    int node = tid >> 4;
    int b = tid & 15;
    if (node >= N_NODES) return;
    int beg = row_ptr[node];
    int end = row_ptr[node + 1];
    float acc = 0.f;
    if (beg < end) {
        int lim = end - 1;
        uint2 r[8];
        #pragma unroll
        for (int j = 0; j < 8; j++) r[j] = entries[min(beg + j, lim)];
        int i = beg;
        while (i + 8 <= end) {
            float yv[8];
            #pragma unroll
            for (int j = 0; j < 8; j++)
                yv[j] = y[(r[j].x & 0x1FFFFu) * BATCH + b];
            uint2 nx[8];
            #pragma unroll
            for (int j = 0; j < 8; j++)
                nx[j] = entries[min(i + 8 + j, lim)];
            #pragma unroll
            for (int j = 0; j < 8; j++)
                acc += __uint_as_float(r[j].y) * yv[j];
            #pragma unroll
            for (int j = 0; j < 8; j++) r[j] = nx[j];
            i += 8;
        }
        if (i < end) {                       // masked epilogue, still batched
            float yv[8];
            #pragma unroll
            for (int j = 0; j < 8; j++)
                yv[j] = y[(r[j].x & 0x1FFFFu) * BATCH + b];
            #pragma unroll
            for (int j = 0; j < 8; j++)
                if (i + j < end)
                    acc += __uint_as_float(r[j].y) * yv[j];
        }
    }
    out[node * BATCH + b] = acc;
}

extern "C" void kernel_launch(void* const* d_in, const int* in_sizes, int n_in,
                              void* d_out, int out_size, void* d_ws, size_t ws_size,
                              hipStream_t stream) {
    const float* x   = (const float*)d_in[0];
    const float* w   = (const float*)d_in[1];
    const int*   row = (const int*)d_in[2];
    const int*   col = (const int*)d_in[3];
    float*       out = (float*)d_out;

    // ---- workspace carve-up (~32.4 MB; proven ws >= 33.25 MB) ----
    char* p = (char*)d_ws;
    uint2* entries = (uint2*)p;  p += (size_t)N_EDGES * sizeof(uint2);           // 25.6 MB
    float* buf     = (float*)p;                                                   // 6.4 MB
    int*   blk_cnt = (int*)buf;  // 800 KB alias: dead before first pull writes buf
    p += (size_t)N_NODES * BATCH * sizeof(float);
    int* totals  = (int*)p;      p += 8192;
    int* bptr    = (int*)p;      p += 8192;
    int* row_ptr = (int*)p;      // 400 KB

    // ---- build exact per-node CSR (once; reused by all 4 layers) ----
    hist_kernel<<<NB, FT, 0, stream>>>(row, blk_cnt);
    colscan_kernel<<<(K_BUCKETS + 255) / 256, 256, 0, stream>>>(blk_cnt, totals);
    scan_kernel<<<1, SCAN_T, 0, stream>>>(totals, bptr, row_ptr);
    fill_kernel<<<NB, FT, 0, stream>>>(row, col, w, bptr, blk_cnt, entries);
    nodesort_kernel<<<K_BUCKETS, 256, 0, stream>>>(bptr, entries, row_ptr);

    // ---- 4 pull layers; d_out doubles as ping-pong buffer, no memsets ----
    const int pgrid = (N_NODES * BATCH + 255) / 256;   // 6250 blocks
    pull_kernel<<<pgrid, 256, 0, stream>>>(x,   entries, row_ptr, buf);  // x   -> buf
    pull_kernel<<<pgrid, 256, 0, stream>>>(buf, entries, row_ptr, out);  // buf -> out
    pull_kernel<<<pgrid, 256, 0, stream>>>(out, entries, row_ptr, buf);  // out -> buf
    pull_kernel<<<pgrid, 256, 0, stream>>>(buf, entries, row_ptr, out);  // buf -> out
}

// Round 9
// 362.497 us; speedup vs baseline: 4.7807x; 1.0037x over previous
//
#include <hip/hip_runtime.h>

#define N_NODES 100000
#define N_EDGES 3200000
#define BATCH 16
#define BKT_SHIFT 6
#define BKT_NODES 64
#define K_BUCKETS 1563                 // ceil(100000/64)
#define NB 256                         // subchunks (E/NB = 12500 exact)
#define SUB (N_EDGES / NB)             // 12500
#define FT 512                         // fill threads per block
#define SCAN_T 256
#define SCAN_C 7                       // 256*7 = 1792 >= 1563
#define CAP 4096                       // nodesort LDS capacity (bucket avg 2047, sigma 45)

// ---- phase 1: per-subchunk LDS histogram of row-buckets ----
__global__ void hist_kernel(const int* __restrict__ row, int* __restrict__ blk_cnt) {
    __shared__ int lh[K_BUCKETS];
    int t = threadIdx.x, blk = blockIdx.x;
    for (int k = t; k < K_BUCKETS; k += 256) lh[k] = 0;
    __syncthreads();
    int base = blk * SUB;
    for (int e = base + t; e < base + SUB; e += 256)
        atomicAdd(&lh[row[e] >> BKT_SHIFT], 1);
    __syncthreads();
    for (int k = t; k < K_BUCKETS; k += 256)
        blk_cnt[k * NB + blk] = lh[k];
}

// ---- phase 2: per-bucket exclusive prefix over the NB subchunks; totals ----
__global__ void colscan_kernel(int* __restrict__ blk_cnt, int* __restrict__ totals) {
    int bkt = blockIdx.x * blockDim.x + threadIdx.x;
    if (bkt >= K_BUCKETS) return;
    int4* p = (int4*)&blk_cnt[bkt * NB];
    int acc = 0;
    for (int q = 0; q < NB / 4; q++) {
        int4 v = p[q];
        int4 o;
        o.x = acc; acc += v.x;
        o.y = acc; acc += v.y;
        o.z = acc; acc += v.z;
        o.w = acc; acc += v.w;
        p[q] = o;
    }
    totals[bkt] = acc;
}

// ---- phase 3: exclusive scan of 1563 bucket totals -> bptr ----
__global__ void scan_kernel(const int* __restrict__ totals, int* __restrict__ bptr,
                            int* __restrict__ row_ptr) {
    __shared__ int s[SCAN_T];
    int t = threadIdx.x;
    int loc[SCAN_C];
    int sum = 0;
    for (int i = 0; i < SCAN_C; i++) {
        int idx = t * SCAN_C + i;
        int v = (idx < K_BUCKETS) ? totals[idx] : 0;
        loc[i] = v;
        sum += v;
    }
    s[t] = sum;
    __syncthreads();
    for (int off = 1; off < SCAN_T; off <<= 1) {   // Hillis-Steele inclusive
        int x = (t >= off) ? s[t - off] : 0;
        __syncthreads();
        s[t] += x;
        __syncthreads();
    }
    int excl = s[t] - sum;
    for (int i = 0; i < SCAN_C; i++) {
        int idx = t * SCAN_C + i;
        if (idx < K_BUCKETS) bptr[idx] = excl;
        excl += loc[i];
    }
    if (t == 0) { bptr[K_BUCKETS] = N_EDGES; row_ptr[N_NODES] = N_EDGES; }
}

// ---- phase 4: LDS counting sort per 12500-edge subchunk, then run copy-out.
// All stores covering one entries line are issued back-to-back by one wave,
// so each line is written once (kills the eviction write-amp of the cursor
// scatter, where a line's 8 stores were spread across the whole kernel).
// record: x = (r_local<<17)|col (col<2^17), y = w bits.
__global__ void __launch_bounds__(FT) fill_kernel(
        const int* __restrict__ row, const int* __restrict__ col,
        const float* __restrict__ w,
        const int* __restrict__ bptr, const int* __restrict__ blk_cnt,
        uint2* __restrict__ entries) {
    __shared__ uint2 sbuf[SUB];          // 100000 B
    __shared__ int lbeg[K_BUCKETS];      // 6252 B
    __shared__ int lcur[K_BUCKETS];      // 6252 B
    __shared__ int sscan[FT];            // 2048 B   (total 114.5 KB)
    int t = threadIdx.x, blk = blockIdx.x;
    for (int k = t; k < K_BUCKETS; k += FT) lcur[k] = 0;
    __syncthreads();
    int base = blk * SUB;
    // pass 1: histogram into lcur
    for (int e = base + t; e < base + SUB; e += FT)
        atomicAdd(&lcur[row[e] >> BKT_SHIFT], 1);
    __syncthreads();
    // block-wide exclusive scan (each thread owns 4 buckets)
    int loc[4];
    int sum = 0;
    #pragma unroll
    for (int j = 0; j < 4; j++) {
        int k = t * 4 + j;
        int v = (k < K_BUCKETS) ? lcur[k] : 0;
        loc[j] = v;
        sum += v;
    }
    sscan[t] = sum;
    __syncthreads();
    for (int off = 1; off < FT; off <<= 1) {
        int x = (t >= off) ? sscan[t - off] : 0;
        __syncthreads();
        sscan[t] += x;
        __syncthreads();
    }
    int excl = sscan[t] - sum;
    #pragma unroll
    for (int j = 0; j < 4; j++) {
        int k = t * 4 + j;
        if (k < K_BUCKETS) { lbeg[k] = excl; lcur[k] = excl; }
        excl += loc[j];
    }
    __syncthreads();
    // pass 2: place records into LDS (bucket-sorted)
    for (int e = base + t; e < base + SUB; e += FT) {
        int r = row[e];
        int bkt = r >> BKT_SHIFT;
        int pos = atomicAdd(&lcur[bkt], 1);
        sbuf[pos] = make_uint2(((unsigned)(r & (BKT_NODES - 1)) << 17) | (unsigned)col[e],
                               __float_as_uint(w[e]));
    }
    __syncthreads();
    // pass 3: 8-lane subgroups copy each bucket run out (coalesced per run;
    // after pass 2, lcur[k] == run end)
    int lane = t & 7;
    for (int k = (t >> 3); k < K_BUCKETS; k += FT / 8) {
        int lb = lbeg[k];
        int le = lcur[k];
        int dst = bptr[k] + blk_cnt[k * NB + blk];
        for (int i = lb + lane; i < le; i += 8)
            entries[dst + (i - lb)] = sbuf[i];
    }
}

// ---- phase 5: in-place per-bucket sort by node (LDS-staged); emits row_ptr ----
__global__ void nodesort_kernel(const int* __restrict__ bptr, uint2* __restrict__ entries,
                                int* __restrict__ row_ptr) {
    __shared__ uint2 ebuf[CAP];          // 32 KB
    __shared__ int nh[BKT_NODES];
    __shared__ int nc[BKT_NODES];
    int t = threadIdx.x, b = blockIdx.x;
    int beg = bptr[b], end = bptr[b + 1];
    int n = min(end - beg, CAP);
    if (t < BKT_NODES) nh[t] = 0;
    __syncthreads();
    for (int k = t; k < n; k += 256) {
        uint2 r = entries[beg + k];
        ebuf[k] = r;
        atomicAdd(&nh[r.x >> 17], 1);
    }
    __syncthreads();
    if (t == 0) {
        int acc = 0;
        for (int i = 0; i < BKT_NODES; i++) {
            int v = nh[i];
            int node = b * BKT_NODES + i;
            if (node < N_NODES) row_ptr[node] = beg + acc;
            nc[i] = acc;
            acc += v;
        }
    }
    __syncthreads();
    for (int k = t; k < n; k += 256) {
        uint2 r = ebuf[k];
        int pos = atomicAdd(&nc[r.x >> 17], 1);
        entries[beg + pos] = r;
    }
}

// ---- layer: node-parallel CSR pull, 8-deep software pipeline, masked epilogue
// (byte-identical to round 8 — clean A/B on fill)
__global__ void __launch_bounds__(256) pull_kernel(const float* __restrict__ y,
                            const uint2* __restrict__ entries,
                            const int* __restrict__ row_ptr,
                            float* __restrict__ out) {
    int tid = blockIdx.x * blockDim.x + threadIdx.x;
    int node = tid >> 4;
    int b = tid & 15;
    if (node >= N_NODES) return;
    int beg = row_ptr[node];
    int end = row_ptr[node + 1];
    float acc = 0.f;
    if (beg < end) {
        int lim = end - 1;
        uint2 r[8];
        #pragma unroll
        for (int j = 0; j < 8; j++) r[j] = entries[min(beg + j, lim)];
        int i = beg;
        while (i + 8 <= end) {
            float yv[8];
            #pragma unroll
            for (int j = 0; j < 8; j++)
                yv[j] = y[(r[j].x & 0x1FFFFu) * BATCH + b];
            uint2 nx[8];
            #pragma unroll
            for (int j = 0; j < 8; j++)
                nx[j] = entries[min(i + 8 + j, lim)];
            #pragma unroll
            for (int j = 0; j < 8; j++)
                acc += __uint_as_float(r[j].y) * yv[j];
            #pragma unroll
            for (int j = 0; j < 8; j++) r[j] = nx[j];
            i += 8;
        }
        if (i < end) {                       // masked epilogue, still batched
            float yv[8];
            #pragma unroll
            for (int j = 0; j < 8; j++)
                yv[j] = y[(r[j].x & 0x1FFFFu) * BATCH + b];
            #pragma unroll
            for (int j = 0; j < 8; j++)
                if (i + j < end)
                    acc += __uint_as_float(r[j].y) * yv[j];
        }
    }
    out[node * BATCH + b] = acc;
}

extern "C" void kernel_launch(void* const* d_in, const int* in_sizes, int n_in,
                              void* d_out, int out_size, void* d_ws, size_t ws_size,
                              hipStream_t stream) {
    const float* x   = (const float*)d_in[0];
    const float* w   = (const float*)d_in[1];
    const int*   row = (const int*)d_in[2];
    const int*   col = (const int*)d_in[3];
    float*       out = (float*)d_out;

    // ---- workspace carve-up (~32.4 MB; proven ws >= 33.2 MB) ----
    char* p = (char*)d_ws;
    uint2* entries = (uint2*)p;  p += (size_t)N_EDGES * sizeof(uint2);           // 25.6 MB
    float* buf     = (float*)p;                                                   // 6.4 MB
    int*   blk_cnt = (int*)buf;  // 1.6 MB alias: dead before first pull writes buf
    p += (size_t)N_NODES * BATCH * sizeof(float);
    int* totals  = (int*)p;      p += 8192;
    int* bptr    = (int*)p;      p += 8192;
    int* row_ptr = (int*)p;      // 400 KB

    // ---- build exact per-node CSR (once; reused by all 4 layers) ----
    hist_kernel<<<NB, 256, 0, stream>>>(row, blk_cnt);
    colscan_kernel<<<(K_BUCKETS + 255) / 256, 256, 0, stream>>>(blk_cnt, totals);
    scan_kernel<<<1, SCAN_T, 0, stream>>>(totals, bptr, row_ptr);
    fill_kernel<<<NB, FT, 0, stream>>>(row, col, w, bptr, blk_cnt, entries);
    nodesort_kernel<<<K_BUCKETS, 256, 0, stream>>>(bptr, entries, row_ptr);

    // ---- 4 pull layers; d_out doubles as ping-pong buffer, no memsets ----
    const int pgrid = (N_NODES * BATCH + 255) / 256;   // 6250 blocks
    pull_kernel<<<pgrid, 256, 0, stream>>>(x,   entries, row_ptr, buf);  // x   -> buf
    pull_kernel<<<pgrid, 256, 0, stream>>>(buf, entries, row_ptr, out);  // buf -> out
    pull_kernel<<<pgrid, 256, 0, stream>>>(out, entries, row_ptr, buf);  // out -> buf
    pull_kernel<<<pgrid, 256, 0, stream>>>(buf, entries, row_ptr, out);  // buf -> out
}